// Round 2
// baseline (176.704 us; speedup 1.0000x reference)
//
#include <hip/hip_runtime.h>

#define N_EDGES 312500
#define D 256          // D_IN == D_HID == 256

typedef __attribute__((ext_vector_type(8)))  short bf16x8;
typedef __attribute__((ext_vector_type(16))) float f32x16;

static __device__ __forceinline__ unsigned short f2bf(float f) {
    union { float f; unsigned u; } c; c.f = f;
    unsigned r = c.u + 0x7fffu + ((c.u >> 16) & 1u);   // RNE
    return (unsigned short)(r >> 16);
}

// Pack W1 [256][256] f32 (row = hidden out, col = in) into bf16 B-fragment order:
// unit u = (nt*16 + kt)*64 + lane  holds 8 bf16:
//   W1 row (nt*32 + (lane&31)), cols kt*16 + (lane>>5)*8 .. +7
__global__ void prep_w1(const float* __restrict__ W1, unsigned short* __restrict__ packed) {
    int t = blockIdx.x * blockDim.x + threadIdx.x;   // 0..8191
    if (t >= 8192) return;
    int lane = t & 63;
    int ktnt = t >> 6;          // 0..127
    int kt = ktnt & 15;
    int nt = ktnt >> 4;
    int r  = nt * 32 + (lane & 31);
    int c0 = kt * 16 + (lane >> 5) * 8;
    const float* src = W1 + r * D + c0;
    unsigned short v[8];
#pragma unroll
    for (int j = 0; j < 8; ++j) v[j] = f2bf(src[j]);
    uint4 u;
    u.x = (unsigned)v[0] | ((unsigned)v[1] << 16);
    u.y = (unsigned)v[2] | ((unsigned)v[3] << 16);
    u.z = (unsigned)v[4] | ((unsigned)v[5] << 16);
    u.w = (unsigned)v[6] | ((unsigned)v[7] << 16);
    reinterpret_cast<uint4*>(packed)[t] = u;
}

__global__ __launch_bounds__(256) void edge_decoder(
    const float* __restrict__ z,
    const int* __restrict__ edge,          // int32 per harness contract
    const unsigned short* __restrict__ w1p,
    const float* __restrict__ b1,
    const float* __restrict__ W2,
    const float* __restrict__ b2,
    float* __restrict__ out)
{
    const int lane = threadIdx.x & 63;
    const int wave = threadIdx.x >> 6;
    const int edgeBase = (blockIdx.x * 4 + wave) * 32;
    if (edgeBase >= N_EDGES) return;          // wave-uniform exit

    const int rowl = lane & 31;               // edge row this lane feeds (A) / hidden col (B,C)
    const int kh   = lane >> 5;               // k-half selector
    int e  = edgeBase + rowl;
    int ec = e < N_EDGES ? e : (N_EDGES - 1); // clamp tail (results discarded)
    int i0 = edge[ec];
    int i1 = edge[N_EDGES + ec];
    const float* z0 = z + (size_t)i0 * D;
    const float* z1 = z + (size_t)i1 * D;

    // ---- gather + product -> A fragments (full K=256 in regs: 16 frags) ----
    bf16x8 a[16];
#pragma unroll
    for (int kt = 0; kt < 16; ++kt) {
        int d0 = kt * 16 + kh * 8;
        float4 p0 = *reinterpret_cast<const float4*>(z0 + d0);
        float4 p1 = *reinterpret_cast<const float4*>(z0 + d0 + 4);
        float4 q0 = *reinterpret_cast<const float4*>(z1 + d0);
        float4 q1 = *reinterpret_cast<const float4*>(z1 + d0 + 4);
        bf16x8 av;
        av[0] = (short)f2bf(p0.x * q0.x);
        av[1] = (short)f2bf(p0.y * q0.y);
        av[2] = (short)f2bf(p0.z * q0.z);
        av[3] = (short)f2bf(p0.w * q0.w);
        av[4] = (short)f2bf(p1.x * q1.x);
        av[5] = (short)f2bf(p1.y * q1.y);
        av[6] = (short)f2bf(p1.z * q1.z);
        av[7] = (short)f2bf(p1.w * q1.w);
        a[kt] = av;
    }

    float partial[16];
#pragma unroll
    for (int i = 0; i < 16; ++i) partial[i] = 0.f;

    const bf16x8* bp = reinterpret_cast<const bf16x8*>(w1p);

    // ---- GEMM1 over hidden-column chunks of 32, fused bias+ELU+W2 dot ----
#pragma unroll 1
    for (int nt = 0; nt < 8; ++nt) {
        f32x16 acc;
#pragma unroll
        for (int i = 0; i < 16; ++i) acc[i] = 0.f;
#pragma unroll
        for (int kt = 0; kt < 16; ++kt) {
            bf16x8 b = bp[(nt * 16 + kt) * 64 + lane];
            acc = __builtin_amdgcn_mfma_f32_32x32x16_bf16(a[kt], b, acc, 0, 0, 0);
        }
        int c = nt * 32 + rowl;               // hidden column this lane holds
        float b1c = b1[c];
        float w2c = W2[c];
#pragma unroll
        for (int r = 0; r < 16; ++r) {
            float h = acc[r] + b1c;
            float v = h > 0.f ? h : (__expf(h) - 1.0f);  // ELU, alpha=1
            partial[r] += v * w2c;
        }
    }

    // ---- reduce across the 32 column-lanes (xor within 32-group) ----
#pragma unroll
    for (int r = 0; r < 16; ++r) {
        float s = partial[r];
        s += __shfl_xor(s, 1);
        s += __shfl_xor(s, 2);
        s += __shfl_xor(s, 4);
        s += __shfl_xor(s, 8);
        s += __shfl_xor(s, 16);
        partial[r] = s;
    }

    if (rowl == 0) {
        float bias2 = b2[0];
#pragma unroll
        for (int r = 0; r < 16; ++r) {
            int rl = (r & 3) + 8 * (r >> 2) + 4 * kh;   // C/D row mapping
            int eo = edgeBase + rl;
            if (eo < N_EDGES) out[eo] = partial[r] + bias2;
        }
    }
}

extern "C" void kernel_launch(void* const* d_in, const int* in_sizes, int n_in,
                              void* d_out, int out_size, void* d_ws, size_t ws_size,
                              hipStream_t stream) {
    const float* z    = (const float*)d_in[0];
    const int*   edge = (const int*)d_in[1];     // harness passes integer inputs as int32
    const float* W1   = (const float*)d_in[2];
    const float* b1   = (const float*)d_in[3];
    const float* W2   = (const float*)d_in[4];
    const float* b2   = (const float*)d_in[5];
    float*       out  = (float*)d_out;
    unsigned short* w1p = (unsigned short*)d_ws;  // 128 KiB packed bf16 W1

    prep_w1<<<32, 256, 0, stream>>>(W1, w1p);

    int blocks = (N_EDGES + 127) / 128;           // 4 waves * 32 edges per block
    edge_decoder<<<blocks, 256, 0, stream>>>(z, edge, w1p, b1, W2, b2, out);
}

// Round 3
// 150.326 us; speedup vs baseline: 1.1755x; 1.1755x over previous
//
#include <hip/hip_runtime.h>
#include <hip/hip_bf16.h>

#define N_EDGES 312500
#define D 256          // D_IN == D_HID == 256
#define BM 128         // edges per block (4 tiles of 32)

typedef __attribute__((ext_vector_type(8)))  short bf16x8;
typedef __attribute__((ext_vector_type(16))) float f32x16;

static __device__ __forceinline__ unsigned short f2bf(float f) {
    union { float f; unsigned u; } c; c.f = f;
    unsigned r = c.u + 0x7fffu + ((c.u >> 16) & 1u);   // RNE
    return (unsigned short)(r >> 16);
}

// Pack W1 [256][256] f32 into bf16 B-fragment order:
// unit u = (nt*16 + kt)*64 + lane holds 8 bf16:
//   W1 row (nt*32 + (lane&31)), cols kt*16 + (lane>>5)*8 .. +7
__global__ void prep_w1(const float* __restrict__ W1, unsigned short* __restrict__ packed) {
    int t = blockIdx.x * blockDim.x + threadIdx.x;   // 0..8191
    if (t >= 8192) return;
    int lane = t & 63;
    int ktnt = t >> 6;
    int kt = ktnt & 15;
    int nt = ktnt >> 4;
    int r  = nt * 32 + (lane & 31);
    int c0 = kt * 16 + (lane >> 5) * 8;
    const float* src = W1 + r * D + c0;
    unsigned short v[8];
#pragma unroll
    for (int j = 0; j < 8; ++j) v[j] = f2bf(src[j]);
    uint4 u;
    u.x = (unsigned)v[0] | ((unsigned)v[1] << 16);
    u.y = (unsigned)v[2] | ((unsigned)v[3] << 16);
    u.z = (unsigned)v[4] | ((unsigned)v[5] << 16);
    u.w = (unsigned)v[6] | ((unsigned)v[7] << 16);
    reinterpret_cast<uint4*>(packed)[t] = u;
}

// LDS A layout: [tile 0..3][kt 0..15][unit 0..63][16B], unit index XOR-swizzled
// by (kt&7) in its low 3 bits. unit (pre-swizzle) = edge_m + 32*kh; 16B holds
// A-frag for row m, k = kt*16 + kh*8 .. +7.
__global__ __launch_bounds__(256, 2) void edge_decoder(
    const float* __restrict__ z,
    const int* __restrict__ edge,
    const unsigned short* __restrict__ w1p,
    const float* __restrict__ b1,
    const float* __restrict__ W2,
    const float* __restrict__ b2,
    float* __restrict__ out)
{
    __shared__ unsigned char ldsRaw[4 * 16 * 64 * 16];   // 64 KiB
    float (*sbuf)[2][32] = reinterpret_cast<float(*)[2][32]>(ldsRaw); // aliases A after barrier

    const int lane = threadIdx.x & 63;
    const int w    = threadIdx.x >> 6;
    const int blockBase = blockIdx.x * BM;

    // ---------- gather stage: wave w builds tile w (coalesced row loads) ----------
    {
        const int kt   = lane >> 2;          // this lane's 4 dims: d = 4*lane..4*lane+3
        const int kh   = (lane >> 1) & 1;
        const int half = lane & 1;
        const int d0   = 4 * lane;
        const int ebase = blockBase + w * 32;
        const int ktx  = kt & 7;
        unsigned char* tbase = ldsRaw + ((w * 16 + kt) << 6) * 16;
#pragma unroll 4
        for (int m = 0; m < 32; ++m) {
            int e  = ebase + m;
            int ec = e < N_EDGES ? e : (N_EDGES - 1);
            int i0 = edge[ec];
            int i1 = edge[N_EDGES + ec];
            float4 p = *reinterpret_cast<const float4*>(z + (size_t)i0 * D + d0);
            float4 q = *reinterpret_cast<const float4*>(z + (size_t)i1 * D + d0);
            __hip_bfloat162 h0 = __float22bfloat162_rn(make_float2(p.x * q.x, p.y * q.y));
            __hip_bfloat162 h1 = __float22bfloat162_rn(make_float2(p.z * q.z, p.w * q.w));
            unsigned u0 = *reinterpret_cast<unsigned*>(&h0);
            unsigned u1 = *reinterpret_cast<unsigned*>(&h1);
            int unit = (m + (kh << 5)) ^ ktx;
            *reinterpret_cast<uint2*>(tbase + unit * 16 + half * 8) = make_uint2(u0, u1);
        }
    }
    __syncthreads();

    // ---------- load A fragments for this wave's two tiles into registers ----------
    const int p2     = w >> 1;           // tile pair: tiles 2p2, 2p2+1
    const int hhalf  = w & 1;            // nt half: nt in [hhalf*4, hhalf*4+4)
    const int rowl   = lane & 31;
    const int kh     = lane >> 5;

    bf16x8 a0[16], a1[16];
#pragma unroll
    for (int kt = 0; kt < 16; ++kt) {
        int sw = lane ^ (kt & 7);
        a0[kt] = *reinterpret_cast<const bf16x8*>(ldsRaw + ((((2 * p2    ) * 16 + kt) << 6) + sw) * 16);
        a1[kt] = *reinterpret_cast<const bf16x8*>(ldsRaw + ((((2 * p2 + 1) * 16 + kt) << 6) + sw) * 16);
    }
    __syncthreads();   // A fully consumed; ldsRaw may be reused as sbuf below

    float part0[16], part1[16];
#pragma unroll
    for (int i = 0; i < 16; ++i) { part0[i] = 0.f; part1[i] = 0.f; }

    const bf16x8* bp = reinterpret_cast<const bf16x8*>(w1p);

#pragma unroll 1
    for (int q = 0; q < 4; ++q) {
        int nt = hhalf * 4 + q;
        f32x16 acc0, acc1;
#pragma unroll
        for (int i = 0; i < 16; ++i) { acc0[i] = 0.f; acc1[i] = 0.f; }
#pragma unroll
        for (int kt = 0; kt < 16; ++kt) {
            bf16x8 b = bp[(nt * 16 + kt) * 64 + lane];
            acc0 = __builtin_amdgcn_mfma_f32_32x32x16_bf16(a0[kt], b, acc0, 0, 0, 0);
            acc1 = __builtin_amdgcn_mfma_f32_32x32x16_bf16(a1[kt], b, acc1, 0, 0, 0);
        }
        int c = nt * 32 + rowl;
        float b1c = b1[c];
        float w2c = W2[c];
#pragma unroll
        for (int r = 0; r < 16; ++r) {
            float h = acc0[r] + b1c;
            part0[r] += (h > 0.f ? h : (__expf(h) - 1.0f)) * w2c;
            float g = acc1[r] + b1c;
            part1[r] += (g > 0.f ? g : (__expf(g) - 1.0f)) * w2c;
        }
    }

    // ---------- reduce across the 32 column-lanes ----------
#pragma unroll
    for (int r = 0; r < 16; ++r) {
        float s = part0[r];
        s += __shfl_xor(s, 1);  s += __shfl_xor(s, 2);
        s += __shfl_xor(s, 4);  s += __shfl_xor(s, 8);
        s += __shfl_xor(s, 16);
        part0[r] = s;
        float t = part1[r];
        t += __shfl_xor(t, 1);  t += __shfl_xor(t, 2);
        t += __shfl_xor(t, 4);  t += __shfl_xor(t, 8);
        t += __shfl_xor(t, 16);
        part1[r] = t;
    }

    if (rowl == 0) {
#pragma unroll
        for (int r = 0; r < 16; ++r) {
            int rl = (r & 3) + 8 * (r >> 2) + 4 * kh;   // C/D row mapping
            sbuf[2 * p2    ][hhalf][rl] = part0[r];
            sbuf[2 * p2 + 1][hhalf][rl] = part1[r];
        }
    }
    __syncthreads();

    if (threadIdx.x < BM) {
        int eo = blockBase + threadIdx.x;
        if (eo < N_EDGES) {
            int tile = threadIdx.x >> 5;
            int row  = threadIdx.x & 31;
            out[eo] = sbuf[tile][0][row] + sbuf[tile][1][row] + b2[0];
        }
    }
}

extern "C" void kernel_launch(void* const* d_in, const int* in_sizes, int n_in,
                              void* d_out, int out_size, void* d_ws, size_t ws_size,
                              hipStream_t stream) {
    const float* z    = (const float*)d_in[0];
    const int*   edge = (const int*)d_in[1];
    const float* W1   = (const float*)d_in[2];
    const float* b1   = (const float*)d_in[3];
    const float* W2   = (const float*)d_in[4];
    const float* b2   = (const float*)d_in[5];
    float*       out  = (float*)d_out;
    unsigned short* w1p = (unsigned short*)d_ws;  // 128 KiB packed bf16 W1

    prep_w1<<<32, 256, 0, stream>>>(W1, w1p);

    int blocks = (N_EDGES + BM - 1) / BM;
    edge_decoder<<<blocks, 256, 0, stream>>>(z, edge, w1p, b1, W2, b2, out);
}

// Round 4
// 142.605 us; speedup vs baseline: 1.2391x; 1.0541x over previous
//
#include <hip/hip_runtime.h>
#include <hip/hip_bf16.h>

#define N_EDGES 312500
#define D 256          // D_IN == D_HID == 256
#define BM 128         // edges per block (4 tiles of 32, one tile per wave)

typedef __attribute__((ext_vector_type(8)))  short bf16x8;
typedef __attribute__((ext_vector_type(16))) float f32x16;

static __device__ __forceinline__ unsigned short f2bf(float f) {
    union { float f; unsigned u; } c; c.f = f;
    unsigned r = c.u + 0x7fffu + ((c.u >> 16) & 1u);   // RNE
    return (unsigned short)(r >> 16);
}

// Pack W1 [256][256] f32 into bf16 B-fragment order:
// unit u = (nt*16 + kt)*64 + lane holds 8 bf16:
//   W1 row (nt*32 + (lane&31)), cols kt*16 + (lane>>5)*8 .. +7
__global__ void prep_w1(const float* __restrict__ W1, unsigned short* __restrict__ packed) {
    int t = blockIdx.x * blockDim.x + threadIdx.x;   // 0..8191
    if (t >= 8192) return;
    int lane = t & 63;
    int ktnt = t >> 6;
    int kt = ktnt & 15;
    int nt = ktnt >> 4;
    int r  = nt * 32 + (lane & 31);
    int c0 = kt * 16 + (lane >> 5) * 8;
    const float* src = W1 + r * D + c0;
    unsigned short v[8];
#pragma unroll
    for (int j = 0; j < 8; ++j) v[j] = f2bf(src[j]);
    uint4 u;
    u.x = (unsigned)v[0] | ((unsigned)v[1] << 16);
    u.y = (unsigned)v[2] | ((unsigned)v[3] << 16);
    u.z = (unsigned)v[4] | ((unsigned)v[5] << 16);
    u.w = (unsigned)v[6] | ((unsigned)v[7] << 16);
    reinterpret_cast<uint4*>(packed)[t] = u;
}

// LDS tile buffer: [kt 0..15][unit 0..63][16B], unit XOR-swizzled by (kt&7).
// unit (pre-swizzle) = m + 32*kh; the 16B is A-frag row m, k=kt*16+kh*8..+7.
__global__ __launch_bounds__(256, 4) void edge_decoder(
    const float* __restrict__ z,
    const int* __restrict__ edge,
    const unsigned short* __restrict__ w1p,
    const float* __restrict__ b1,
    const float* __restrict__ W2,
    const float* __restrict__ b2,
    float* __restrict__ out)
{
    __shared__ unsigned char ldsA[2][16 * 64 * 16];   // 2 x 16 KiB double buffer

    const int lane = threadIdx.x & 63;
    const int w    = threadIdx.x >> 6;
    const int blockBase = blockIdx.x * BM;

    // gather-phase lane mapping: lane owns dims d0..d0+3 of each row
    const int gkt  = lane >> 2;
    const int gkh  = (lane >> 1) & 1;
    const int ghal = lane & 1;
    const int d0   = 4 * lane;
    const int gktx = gkt & 7;

    // all 4 waves cooperatively gather one 32-edge tile (8 edges per wave)
    auto gather8 = [&](int t, int b) {
        unsigned char* tb = ldsA[b] + (gkt << 10);
        int ebase = blockBase + t * 32 + w * 8;
#pragma unroll
        for (int j = 0; j < 8; ++j) {
            int e  = ebase + j;
            int ec = e < N_EDGES ? e : (N_EDGES - 1);   // clamp tail
            int i0 = edge[ec];
            int i1 = edge[N_EDGES + ec];
            float4 p = *reinterpret_cast<const float4*>(z + (size_t)i0 * D + d0);
            float4 q = *reinterpret_cast<const float4*>(z + (size_t)i1 * D + d0);
            __hip_bfloat162 h0 = __float22bfloat162_rn(make_float2(p.x * q.x, p.y * q.y));
            __hip_bfloat162 h1 = __float22bfloat162_rn(make_float2(p.z * q.z, p.w * q.w));
            int m = w * 8 + j;
            int unit = (m + (gkh << 5)) ^ gktx;
            *reinterpret_cast<uint2*>(tb + unit * 16 + ghal * 8) =
                make_uint2(*reinterpret_cast<unsigned*>(&h0),
                           *reinterpret_cast<unsigned*>(&h1));
        }
    };

    bf16x8 a[16];
    auto readA = [&](int b) {
#pragma unroll
        for (int kt = 0; kt < 16; ++kt)
            a[kt] = *reinterpret_cast<const bf16x8*>(
                ldsA[b] + (kt << 10) + ((lane ^ (kt & 7)) << 4));
    };

    // pipelined gather: tile t -> buffer t&1; wave w consumes tile w
    gather8(0, 0); __syncthreads();
    gather8(1, 1); if (w == 0) readA(0); __syncthreads();
    gather8(2, 0); if (w == 1) readA(1); __syncthreads();
    gather8(3, 1); if (w == 2) readA(0); __syncthreads();
    if (w == 3) readA(1);

    // ---- GEMM1 (full 8 nt per wave) fused bias+ELU+W2 dot ----
    const int rowl = lane & 31;
    const int kh   = lane >> 5;

    float part[16];
#pragma unroll
    for (int i = 0; i < 16; ++i) part[i] = 0.f;

    const bf16x8* bp = reinterpret_cast<const bf16x8*>(w1p);

#pragma unroll 1
    for (int nt = 0; nt < 8; ++nt) {
        f32x16 acc;
#pragma unroll
        for (int i = 0; i < 16; ++i) acc[i] = 0.f;
#pragma unroll
        for (int kt = 0; kt < 16; ++kt) {
            bf16x8 bfrag = bp[(nt * 16 + kt) * 64 + lane];
            acc = __builtin_amdgcn_mfma_f32_32x32x16_bf16(a[kt], bfrag, acc, 0, 0, 0);
        }
        int c = nt * 32 + rowl;
        float b1c = b1[c];
        float w2c = W2[c];
#pragma unroll
        for (int r = 0; r < 16; ++r) {
            float h = acc[r] + b1c;
            part[r] += (h > 0.f ? h : (__expf(h) - 1.0f)) * w2c;
        }
    }

    // ---- reduce across the 32 column-lanes ----
#pragma unroll
    for (int r = 0; r < 16; ++r) {
        float s = part[r];
        s += __shfl_xor(s, 1);  s += __shfl_xor(s, 2);
        s += __shfl_xor(s, 4);  s += __shfl_xor(s, 8);
        s += __shfl_xor(s, 16);
        part[r] = s;
    }

    if (rowl == 0) {
        float bias2 = b2[0];
        int ebase = blockBase + w * 32;
#pragma unroll
        for (int r = 0; r < 16; ++r) {
            int rl = (r & 3) + 8 * (r >> 2) + 4 * kh;   // C/D row mapping
            int eo = ebase + rl;
            if (eo < N_EDGES) out[eo] = part[r] + bias2;
        }
    }
}

extern "C" void kernel_launch(void* const* d_in, const int* in_sizes, int n_in,
                              void* d_out, int out_size, void* d_ws, size_t ws_size,
                              hipStream_t stream) {
    const float* z    = (const float*)d_in[0];
    const int*   edge = (const int*)d_in[1];
    const float* W1   = (const float*)d_in[2];
    const float* b1   = (const float*)d_in[3];
    const float* W2   = (const float*)d_in[4];
    const float* b2   = (const float*)d_in[5];
    float*       out  = (float*)d_out;
    unsigned short* w1p = (unsigned short*)d_ws;  // 128 KiB packed bf16 W1

    prep_w1<<<32, 256, 0, stream>>>(W1, w1p);

    int blocks = (N_EDGES + BM - 1) / BM;
    edge_decoder<<<blocks, 256, 0, stream>>>(z, edge, w1p, b1, W2, b2, out);
}